// Round 8
// baseline (194.291 us; speedup 1.0000x reference)
//
#include <hip/hip_runtime.h>
#include <math.h>

typedef float f32x2 __attribute__((ext_vector_type(2)));
typedef float f32x4 __attribute__((ext_vector_type(4)));

// Problem constants (setup_inputs fixed: 1x3x2048x2048 fp32)
#define HH    2048
#define WW    2048
#define NCH   3
#define NOUT  2038          // 2048 - 10 (VALID 11-tap twice)
#define OWID  64            // output tile width
#define OHGT  11            // output tile height (16->11: LDS under 40 KB -> 4 blk/CU)
#define IHGT  21            // OHGT + 10
#define SWP   76            // sxy stride in (x,y) pairs (>=76: stage A writes 4 pairs at c0<=72)
#define HABW  64            // hbAB stride in f32x4 — no pad: stage B/C access is row-local
#define HCW   64            // hbC stride in floats
#define NTX   32            // ceil(2038/64)
#define NTY   186           // ceil(2038/11)
#define NBLOCKS (NTX*NTY*NCH)   // 17856
#define NOUT_TOTAL 12460332.0f  // 3 * 2038 * 2038

// SSIM per-pixel term. Scalar args, compile-time indices at call sites only
// (runtime pointer-select of register arrays caused scratch demotion in R2:
// 664 MB spill writes). rcpf: denominators >= 9e-4, rel err ~1e-6 vs 2e-2
// threshold.
__device__ __forceinline__ float ssim_term(float mu1, float mu2,
                                           float b11, float b22, float b12) {
    const float c1v = 1e-4f, c2v = 9e-4f;
    float mu1sq = mu1 * mu1;
    float mu2sq = mu2 * mu2;
    float mu12  = mu1 * mu2;
    float s11 = b11 - mu1sq;
    float s22 = b22 - mu2sq;
    float s12 = b12 - mu12;
    float csn = 2.f * s12 + c2v;
    float csd = s11 + s22 + c2v;
    float ln  = 2.f * mu12 + c1v;
    float ld  = mu1sq + mu2sq + c1v;
    return (csn * ln) * __builtin_amdgcn_rcpf(csd * ld);
}

// fp32 end-to-end (R5 fp16 regressed). Packed layout: hbAB=(mu1,mu2,xx,yy)
// as f32x4 -> stage C does 1 b128 + 1 b32 per window row (was 2 b64 + b32),
// f32x4 fma lowers to 2 v_pk_fma_f32.
// __launch_bounds__(256,2): (256,4) capped VGPRs at 64 -> massive spill (R3).
__global__ __launch_bounds__(256, 2)
void ssim_main(const float* __restrict__ x, const float* __restrict__ y,
               float* __restrict__ partials) {
    __shared__ f32x2 sxy[IHGT][SWP];     // interleaved (x,y): 12.5 KB
    __shared__ f32x4 hbAB[IHGT][HABW];   // (mu1,mu2,xx,yy) h-blur: 21.0 KB
    __shared__ float hbC[IHGT][HCW];     // xy h-blur: 5.25 KB
    __shared__ float wsum[4];            // total 38.7 KB -> 4 blocks/CU

    const int tid = threadIdx.x;
    const int gx0 = blockIdx.x * OWID;
    const int gy0 = blockIdx.y * OHGT;
    const float* xb = x + (size_t)blockIdx.z * HH * WW;
    const float* yb = y + (size_t)blockIdx.z * HH * WW;

    // Gaussian weights (11 taps, sigma 1.5), normalized — matches jnp f32
    float w[11];
    {
        float s = 0.f;
        #pragma unroll
        for (int i = 0; i < 11; ++i) {
            float d = (float)(i - 5);
            w[i] = expf(-d * d / 4.5f);
            s += w[i];
        }
        float inv = 1.f / s;
        #pragma unroll
        for (int i = 0; i < 11; ++i) w[i] *= inv;
    }

    // ---- Stage A: global -> LDS interleaved (x,y) pairs. float4 global
    // loads, 2x b128 LDS writes. Edge-clamped values feed only guarded
    // outputs. 21*19 = 399 units. ----
    for (int u = tid; u < IHGT * 19; u += 256) {
        int r  = u / 19;                 // compiler magic-mul
        int c0 = (u - r * 19) * 4;       // pair cols 0..72 (74,75 in-row pad)
        int gy = gy0 + r; if (gy > HH - 1) gy = HH - 1;
        const float* xr = xb + (size_t)gy * WW;
        const float* yr = yb + (size_t)gy * WW;
        int gxc = gx0 + c0;
        float4 xf, yf;
        if (gxc + 4 <= WW) {
            xf = *(const float4*)(xr + gxc);
            yf = *(const float4*)(yr + gxc);
        } else {
            int g0 = gxc     < WW ? gxc     : WW - 1;
            int g1 = gxc + 1 < WW ? gxc + 1 : WW - 1;
            int g2 = gxc + 2 < WW ? gxc + 2 : WW - 1;
            int g3 = gxc + 3 < WW ? gxc + 3 : WW - 1;
            xf = make_float4(xr[g0], xr[g1], xr[g2], xr[g3]);
            yf = make_float4(yr[g0], yr[g1], yr[g2], yr[g3]);
        }
        *(f32x4*)&sxy[r][c0]     = (f32x4){xf.x, yf.x, xf.y, yf.y};
        *(f32x4*)&sxy[r][c0 + 2] = (f32x4){xf.z, yf.z, xf.w, yf.w};
    }
    __syncthreads();

    // ---- Stage B: horizontal blur, 4 output cols per unit. Per tap per col:
    // pk_fma(mu pair) + pk_fma(sq pair) + fma(xy) = 3 slots. 21*16 = 336
    // units. ----
    for (int u = tid; u < IHGT * 16; u += 256) {
        int r  = u >> 4;
        int c0 = (u & 15) * 4;
        f32x2 p[16];
        #pragma unroll
        for (int t = 0; t < 8; ++t) {
            f32x4 raw = *(const f32x4*)&sxy[r][c0 + 2 * t];
            p[2 * t]     = (f32x2){raw.x, raw.y};
            p[2 * t + 1] = (f32x2){raw.z, raw.w};
        }
        f32x2 q[14]; float pr[14];
        #pragma unroll
        for (int t = 0; t < 14; ++t) {
            q[t]  = p[t] * p[t];         // v_pk_mul_f32: (x^2, y^2)
            pr[t] = p[t].x * p[t].y;     // x*y
        }
        f32x2 hA[4] = {}, hB[4] = {};
        float hC[4] = {};
        #pragma unroll
        for (int k = 0; k < 11; ++k) {
            f32x2 wk2 = (f32x2){w[k], w[k]};
            #pragma unroll
            for (int j = 0; j < 4; ++j) {
                hA[j] = __builtin_elementwise_fma(wk2, p[j + k], hA[j]);
                hB[j] = __builtin_elementwise_fma(wk2, q[j + k], hB[j]);
                hC[j] = fmaf(w[k], pr[j + k], hC[j]);
            }
        }
        #pragma unroll
        for (int j = 0; j < 4; ++j)
            hbAB[r][c0 + j] = (f32x4){hA[j].x, hA[j].y, hB[j].x, hB[j].y};
        *(float4*)&hbC[r][c0] = make_float4(hC[0], hC[1], hC[2], hC[3]);
    }
    __syncthreads();

    // ---- Stage C: vertical blur, 1 col per thread; wave rg=0..2 -> 3 rows,
    // rg=3 -> 2 rows (wave-uniform split of 11 = 3+3+3+2). Window reads:
    // 13 x (b128 + b32), compile-time register indices throughout. ----
    float partial = 0.f;
    {
        const int col = tid & 63;
        const int rg  = tid >> 6;         // wave id, 0..3
        const int r0  = rg * 3;           // first output row of this wave
        f32x4 vAB[13]; float vC[13];
        #pragma unroll
        for (int j = 0; j < 13; ++j) {
            int rr = r0 + j;
            if (rr < IHGT) {              // wave-uniform; false only rg=3,j=12
                vAB[j] = hbAB[rr][col];
                vC[j]  = hbC[rr][col];
            } else {
                vAB[j] = (f32x4){0.f, 0.f, 0.f, 0.f};
                vC[j]  = 0.f;
            }
        }
        const int ocol = gx0 + col;
        #pragma unroll
        for (int i = 0; i < 3; ++i) {
            f32x4 aAB = {0.f, 0.f, 0.f, 0.f};
            float aC = 0.f;
            #pragma unroll
            for (int k = 0; k < 11; ++k) {
                f32x4 wk4 = (f32x4){w[k], w[k], w[k], w[k]};
                aAB = __builtin_elementwise_fma(wk4, vAB[i + k], aAB);
                aC  = fmaf(w[k], vC[i + k], aC);
            }
            int orow = gy0 + r0 + i;
            if ((rg < 3 || i < 2) && orow < NOUT && ocol < NOUT)
                partial += ssim_term(aAB.x, aAB.y, aAB.z, aAB.w, aC);
        }
    }

    // ---- Reduction: wave shuffle -> block -> one plain store per block. ----
    #pragma unroll
    for (int off = 32; off > 0; off >>= 1)
        partial += __shfl_down(partial, off, 64);
    if ((tid & 63) == 0) wsum[tid >> 6] = partial;
    __syncthreads();
    if (tid == 0) {
        int bid = (blockIdx.z * gridDim.y + blockIdx.y) * gridDim.x + blockIdx.x;
        partials[bid] = wsum[0] + wsum[1] + wsum[2] + wsum[3];
    }
}

__global__ __launch_bounds__(256)
void ssim_finalize(const float* __restrict__ partials, float* __restrict__ out) {
    __shared__ float ws[4];
    float s = 0.f;
    // NBLOCKS = 17856 = 4464 float4s
    for (int i = threadIdx.x; i < NBLOCKS / 4; i += 256) {
        float4 v = ((const float4*)partials)[i];
        s += (v.x + v.y) + (v.z + v.w);
    }
    #pragma unroll
    for (int off = 32; off > 0; off >>= 1)
        s += __shfl_down(s, off, 64);
    if ((threadIdx.x & 63) == 0) ws[threadIdx.x >> 6] = s;
    __syncthreads();
    if (threadIdx.x == 0)
        out[0] = 1.f - (ws[0] + ws[1] + ws[2] + ws[3]) / NOUT_TOTAL;
}

extern "C" void kernel_launch(void* const* d_in, const int* in_sizes, int n_in,
                              void* d_out, int out_size, void* d_ws, size_t ws_size,
                              hipStream_t stream) {
    const float* x = (const float*)d_in[0];
    const float* y = (const float*)d_in[1];
    float* out = (float*)d_out;
    float* partials = (float*)d_ws;   // NBLOCKS floats = 69.8 KB of scratch

    dim3 grid(NTX, NTY, NCH);
    ssim_main<<<grid, dim3(256), 0, stream>>>(x, y, partials);
    ssim_finalize<<<1, 256, 0, stream>>>(partials, out);
}

// Round 9
// 180.291 us; speedup vs baseline: 1.0776x; 1.0776x over previous
//
#include <hip/hip_runtime.h>
#include <math.h>

typedef float f32x2 __attribute__((ext_vector_type(2)));
typedef float f32x4 __attribute__((ext_vector_type(4)));

// Problem constants (setup_inputs fixed: 1x3x2048x2048 fp32)
#define HH    2048
#define WW    2048
#define NCH   3
#define NOUT  2038          // 2048 - 10 (VALID 11-tap twice)
#define OWID  64            // strip width
#define OH    128           // strip height (outputs per block)
#define CROWS 16            // chunk rows
#define BUF   32            // circular h-blur buffer slots (pow2 -> &31)
#define SWP   76            // sxy stride in (x,y) pairs (stage A writes 4 pairs at c0<=72)
#define HAW   66            // hbA/hbB stride in pairs: 528B rows (R7-proven, b64 2-way free)
#define HCW   68            // hbC stride in floats: 272B rows
#define NTX   32            // 2048/64
#define NTY   16            // 2048/128
#define NBLOCKS (NTX*NTY*NCH)   // 1536
#define NOUT_TOTAL 12460332.0f  // 3 * 2038 * 2038

// SSIM per-pixel term. Scalar args, compile-time indices at call sites only
// (runtime pointer-select of register arrays caused scratch demotion in R2:
// 664 MB spill writes). rcpf: denominators >= 9e-4, rel err ~1e-6 vs 2e-2
// threshold.
__device__ __forceinline__ float ssim_term(float mu1, float mu2,
                                           float b11, float b22, float b12) {
    const float c1v = 1e-4f, c2v = 9e-4f;
    float mu1sq = mu1 * mu1;
    float mu2sq = mu2 * mu2;
    float mu12  = mu1 * mu2;
    float s11 = b11 - mu1sq;
    float s22 = b22 - mu2sq;
    float s12 = b12 - mu12;
    float csn = 2.f * s12 + c2v;
    float csd = s11 + s22 + c2v;
    float ln  = 2.f * mu12 + c1v;
    float ld  = mu1sq + mu2sq + c1v;
    return (csn * ln) * __builtin_amdgcn_rcpf(csd * ld);
}

// Persistent column-strip kernel: each block owns a 64x128 strip and h-blurs
// every image row ONCE into a 32-slot circular LDS buffer (vs tiled R7:
// 1.625x re-blur of the 10-row vertical halo). f32x2/b64 hb layout per R7
// (R8's f32x4/b128 doubled bank conflicts: 16B lane stride). fp32 throughout
// (R5 fp16 regressed). __launch_bounds__(256,2): (256,4) caps VGPR at 64 ->
// catastrophic spill (R3).
__global__ __launch_bounds__(256, 2)
void ssim_main(const float* __restrict__ x, const float* __restrict__ y,
               float* __restrict__ partials) {
    __shared__ f32x2 sxy[CROWS][SWP];    // staged (x,y) pairs: 9.5 KB
    __shared__ f32x2 hbA[BUF][HAW];      // (mu1,mu2) h-blur ring: 16.5 KB
    __shared__ f32x2 hbB[BUF][HAW];      // (xx,yy)  h-blur ring: 16.5 KB
    __shared__ float hbC[BUF][HCW];      // xy       h-blur ring:  8.5 KB
    __shared__ float wsum[4];            // total 51.0 KB -> 3 blocks/CU

    const int tid = threadIdx.x;
    const int gx0 = blockIdx.x * OWID;
    const int gy0 = blockIdx.y * OH;     // multiple of 32 -> (gy0+r)&31 == r&31
    const float* xb = x + (size_t)blockIdx.z * HH * WW;
    const float* yb = y + (size_t)blockIdx.z * HH * WW;

    // Gaussian weights (11 taps, sigma 1.5), normalized — matches jnp f32
    float w[11];
    {
        float s = 0.f;
        #pragma unroll
        for (int i = 0; i < 11; ++i) {
            float d = (float)(i - 5);
            w[i] = expf(-d * d / 4.5f);
            s += w[i];
        }
        float inv = 1.f / s;
        #pragma unroll
        for (int i = 0; i < 11; ++i) w[i] *= inv;
    }

    // Stage A: load 16 strip rows [base, base+16) into sxy (interleaved pairs).
    auto loadA = [&](int base) {
        for (int u = tid; u < CROWS * 19; u += 256) {
            int lr = u / 19;                 // 0..15 (magic-mul)
            int c0 = (u - lr * 19) * 4;      // pair col 0..72
            int gy = gy0 + base + lr; if (gy > HH - 1) gy = HH - 1;
            const float* xr = xb + (size_t)gy * WW;
            const float* yr = yb + (size_t)gy * WW;
            int gxc = gx0 + c0;
            float4 xf, yf;
            if (gxc + 4 <= WW) {
                xf = *(const float4*)(xr + gxc);
                yf = *(const float4*)(yr + gxc);
            } else {  // right-edge clamp; feeds only guarded outputs
                int g0 = gxc     < WW ? gxc     : WW - 1;
                int g1 = gxc + 1 < WW ? gxc + 1 : WW - 1;
                int g2 = gxc + 2 < WW ? gxc + 2 : WW - 1;
                int g3 = gxc + 3 < WW ? gxc + 3 : WW - 1;
                xf = make_float4(xr[g0], xr[g1], xr[g2], xr[g3]);
                yf = make_float4(yr[g0], yr[g1], yr[g2], yr[g3]);
            }
            *(f32x4*)&sxy[lr][c0]     = (f32x4){xf.x, yf.x, xf.y, yf.y};
            *(f32x4*)&sxy[lr][c0 + 2] = (f32x4){xf.z, yf.z, xf.w, yf.w};
        }
    };

    // Stage B: h-blur the 16 staged rows into ring slots (base+lr)&31.
    // Exactly 1 unit per thread. Per tap per col: 2 pk_fma + 1 fma.
    auto blurB = [&](int base) {
        int lr = tid >> 4;
        int c0 = (tid & 15) * 4;
        int slot = (base + lr) & (BUF - 1);
        f32x2 p[16];
        #pragma unroll
        for (int t = 0; t < 8; ++t) {
            f32x4 raw = *(const f32x4*)&sxy[lr][c0 + 2 * t];
            p[2 * t]     = (f32x2){raw.x, raw.y};
            p[2 * t + 1] = (f32x2){raw.z, raw.w};
        }
        f32x2 q[14]; float pr[14];
        #pragma unroll
        for (int t = 0; t < 14; ++t) {
            q[t]  = p[t] * p[t];             // v_pk_mul_f32
            pr[t] = p[t].x * p[t].y;
        }
        f32x2 hA[4] = {}, hB[4] = {};
        float hC[4] = {};
        #pragma unroll
        for (int k = 0; k < 11; ++k) {
            f32x2 wk2 = (f32x2){w[k], w[k]};
            #pragma unroll
            for (int j = 0; j < 4; ++j) {
                hA[j] = __builtin_elementwise_fma(wk2, p[j + k], hA[j]);
                hB[j] = __builtin_elementwise_fma(wk2, q[j + k], hB[j]);
                hC[j] = fmaf(w[k], pr[j + k], hC[j]);
            }
        }
        // b128 stores (rows 528B/272B, c0 mult of 4 -> 16B-aligned)
        *(f32x4*)&hbA[slot][c0]     = (f32x4){hA[0].x, hA[0].y, hA[1].x, hA[1].y};
        *(f32x4*)&hbA[slot][c0 + 2] = (f32x4){hA[2].x, hA[2].y, hA[3].x, hA[3].y};
        *(f32x4*)&hbB[slot][c0]     = (f32x4){hB[0].x, hB[0].y, hB[1].x, hB[1].y};
        *(f32x4*)&hbB[slot][c0 + 2] = (f32x4){hB[2].x, hB[2].y, hB[3].x, hB[3].y};
        *(float4*)&hbC[slot][c0]    = make_float4(hC[0], hC[1], hC[2], hC[3]);
    };

    float partial = 0.f;

    // Prologue: rows 0..31 loaded + h-blurred once.
    loadA(0);  __syncthreads(); blurB(0);  __syncthreads();
    loadA(16); __syncthreads(); blurB(16); __syncthreads();

    // Main loop: 8 chunks of 16 output rows. Invariant at chunk m: ring holds
    // h-rows [16m, 16m+32); window for outputs [16m, 16m+16) needs rows
    // <= 16m+25. After C, rows [16m,16m+16) are dead -> overwritten by the
    // next 16 h-rows.
    for (int m = 0; m < 8; ++m) {
        const int o0 = m * CROWS;
        {   // Stage C: v-blur, 1 col x 4 rows per thread, batched b64 reads.
            const int col = tid & 63;
            const int r0  = o0 + (tid >> 6) * 4;
            f32x2 vA[14], vB[14]; float vC[14];
            #pragma unroll
            for (int j = 0; j < 14; ++j) {
                int slot = (r0 + j) & (BUF - 1);
                vA[j] = hbA[slot][col];
                vB[j] = hbB[slot][col];
                vC[j] = hbC[slot][col];
            }
            const int ocol = gx0 + col;
            #pragma unroll
            for (int i = 0; i < 4; ++i) {
                f32x2 aA = {0.f, 0.f}, aB = {0.f, 0.f};
                float aC = 0.f;
                #pragma unroll
                for (int k = 0; k < 11; ++k) {
                    f32x2 wk2 = (f32x2){w[k], w[k]};
                    aA = __builtin_elementwise_fma(wk2, vA[i + k], aA);
                    aB = __builtin_elementwise_fma(wk2, vB[i + k], aB);
                    aC = fmaf(w[k], vC[i + k], aC);
                }
                int orow = gy0 + r0 + i;
                if (orow < NOUT && ocol < NOUT)
                    partial += ssim_term(aA.x, aA.y, aB.x, aB.y, aC);
            }
        }
        __syncthreads();   // C reads done before B overwrites those slots
        if (m < 7) {
            loadA(32 + o0); __syncthreads();
            blurB(32 + o0); __syncthreads();
        }
    }

    // Reduction: wave shuffle -> block -> one plain store per block.
    #pragma unroll
    for (int off = 32; off > 0; off >>= 1)
        partial += __shfl_down(partial, off, 64);
    if ((tid & 63) == 0) wsum[tid >> 6] = partial;
    __syncthreads();
    if (tid == 0) {
        int bid = (blockIdx.z * gridDim.y + blockIdx.y) * gridDim.x + blockIdx.x;
        partials[bid] = wsum[0] + wsum[1] + wsum[2] + wsum[3];
    }
}

__global__ __launch_bounds__(256)
void ssim_finalize(const float* __restrict__ partials, float* __restrict__ out) {
    __shared__ float ws[4];
    float s = 0.f;
    // NBLOCKS = 1536 = 384 float4s
    for (int i = threadIdx.x; i < NBLOCKS / 4; i += 256) {
        float4 v = ((const float4*)partials)[i];
        s += (v.x + v.y) + (v.z + v.w);
    }
    #pragma unroll
    for (int off = 32; off > 0; off >>= 1)
        s += __shfl_down(s, off, 64);
    if ((threadIdx.x & 63) == 0) ws[threadIdx.x >> 6] = s;
    __syncthreads();
    if (threadIdx.x == 0)
        out[0] = 1.f - (ws[0] + ws[1] + ws[2] + ws[3]) / NOUT_TOTAL;
}

extern "C" void kernel_launch(void* const* d_in, const int* in_sizes, int n_in,
                              void* d_out, int out_size, void* d_ws, size_t ws_size,
                              hipStream_t stream) {
    const float* x = (const float*)d_in[0];
    const float* y = (const float*)d_in[1];
    float* out = (float*)d_out;
    float* partials = (float*)d_ws;   // NBLOCKS floats = 6 KB of scratch

    dim3 grid(NTX, NTY, NCH);
    ssim_main<<<grid, dim3(256), 0, stream>>>(x, y, partials);
    ssim_finalize<<<1, 256, 0, stream>>>(partials, out);
}